// Round 2
// baseline (467.877 us; speedup 1.0000x reference)
//
#include <hip/hip_runtime.h>

#define N_NODES 50000
#define E_EDGES 800000
#define R_REL 3
#define HID 128
#define HEADS 4
#define CAP 64               // per-(relation,node) slot capacity; P(indeg>63) ~ 1e-19

typedef __attribute__((ext_vector_type(8))) short short8;   // 8 bf16 in 4 VGPRs
typedef __attribute__((ext_vector_type(4))) float float4v;  // MFMA C/D frag

__device__ __forceinline__ unsigned short f2bf(float f) {
    unsigned int u = __float_as_uint(f);
    u += 0x7fffu + ((u >> 16) & 1u);     // round-to-nearest-even
    return (unsigned short)(u >> 16);
}
__device__ __forceinline__ float bf_lo(unsigned int u) { return __uint_as_float(u << 16); }
__device__ __forceinline__ float bf_hi(unsigned int u) { return __uint_as_float(u & 0xffff0000u); }

// ---------------- dispatch 1: setup (W^T, gw) + direct edge scatter (global atomics) ----------------
// Global atomicAdd on cnt is L2-side on CDNA4; ~16 edges/address avg -> negligible contention.
// This replaces the fillA-regions-fillB two-phase bucketing (which had a 96-block serial drain).
#define WCONV_T (R_REL * HID * HID)          // 49152
#define SETUP_BLKS 193                        // 192 for W^T + 1 spare thread block for gw
#define SCAT_CHUNK 2048                       // edges per scatter block
#define SCAT_PER_REL ((E_EDGES + SCAT_CHUNK - 1) / SCAT_CHUNK)   // 391
#define SCAT_BLKS (R_REL * SCAT_PER_REL)      // 1173
__global__ __launch_bounds__(256) void setup_scatter_kernel(const float* __restrict__ W,
                                                            const float* __restrict__ gate,
                                                            const int* __restrict__ edge_idx,
                                                            unsigned short* __restrict__ wtb,
                                                            float* __restrict__ gw_out,
                                                            int* __restrict__ cnt,
                                                            unsigned short* __restrict__ slots) {
    int bid = blockIdx.x;
    if (bid < SETUP_BLKS) {
        int tid = bid * 256 + threadIdx.x;
        if (tid < WCONV_T) {
            int r = tid >> 14, rem = tid & 16383, n = rem >> 7, k = rem & 127;
            wtb[tid] = f2bf(W[r * 16384 + k * 128 + n]);   // wtb[r][n][k] = W[r][k][n]
        } else if (tid == WCONV_T) {
            float g0 = gate[0], g1 = gate[1], g2 = gate[2];
            float mg = fmaxf(g0, fmaxf(g1, g2));
            float e0 = __expf(g0 - mg), e1 = __expf(g1 - mg), e2 = __expf(g2 - mg);
            float inv = 1.f / (e0 + e1 + e2);
            gw_out[0] = e0 * inv; gw_out[1] = e1 * inv; gw_out[2] = e2 * inv;
        }
        return;
    }
    int fb = bid - SETUP_BLKS;
    int r = fb / SCAT_PER_REL, c = fb % SCAT_PER_REL;
    const int4* s4 = (const int4*)(edge_idx + (long)r * 2 * E_EDGES);
    const int4* d4 = (const int4*)(edge_idx + (long)r * 2 * E_EDGES + E_EDGES);
    int* cr = cnt + r * N_NODES;
    unsigned short* sr = slots + (long)r * N_NODES * CAP;
    int base4 = c * (SCAT_CHUNK / 4);          // int4 index base; E/4 = 200000
#pragma unroll
    for (int k = 0; k < 2; ++k) {
        int i = base4 + k * 256 + threadIdx.x;
        if (i < E_EDGES / 4) {
            int4 sv = s4[i];
            int4 dv = d4[i];
#pragma unroll
            for (int j = 0; j < 4; ++j) {
                int dst = (j == 0) ? dv.x : (j == 1) ? dv.y : (j == 2) ? dv.z : dv.w;
                int src = (j == 0) ? sv.x : (j == 1) ? sv.y : (j == 2) ? sv.z : sv.w;
                int p_ = atomicAdd(&cr[dst], 1);
                if (p_ < CAP) sr[(long)dst * CAP + p_] = (unsigned short)src;
            }
        }
    }
}

// ---------------- dispatch 2: pure MFMA GEMM + alpha epilogue ----------------
// A = W^T (rows=channels), B = x^T in-register bf16 -> D[channel reg][node lane].
#define STRIPS 3125
#define BLK_PER_REL 782                       // ceil(3125/4)
#define GEMM_BLKS (R_REL * BLK_PER_REL)       // 2346
__global__ __launch_bounds__(256) void gemm_kernel(const float* __restrict__ x,
                                                   const unsigned short* __restrict__ wtb,
                                                   unsigned short* __restrict__ hb,
                                                   const float* __restrict__ att_src,
                                                   const float* __restrict__ att_dst,
                                                   float* __restrict__ asrc,
                                                   float* __restrict__ adst) {
    int gb = blockIdx.x;
    int r = gb / BLK_PER_REL;
    int sb = gb % BLK_PER_REL;
    int strip = sb * 4 + (threadIdx.x >> 6);
    if (strip >= STRIPS) return;
    int lane = threadIdx.x & 63;
    int m = lane & 15, quad = lane >> 4;

    // B-operand: lane m reads fp32 row strip*16+m, k-chunk quad*8, converts to bf16 in-register
    const float* xrow = x + (long)(strip * 16 + m) * HID + quad * 8;
    short8 B[4];
#pragma unroll
    for (int kc = 0; kc < 4; ++kc) {
        float4 f0 = *(const float4*)(xrow + kc * 32);
        float4 f1 = *(const float4*)(xrow + kc * 32 + 4);
        short8 b;
        b[0] = (short)f2bf(f0.x); b[1] = (short)f2bf(f0.y);
        b[2] = (short)f2bf(f0.z); b[3] = (short)f2bf(f0.w);
        b[4] = (short)f2bf(f1.x); b[5] = (short)f2bf(f1.y);
        b[6] = (short)f2bf(f1.z); b[7] = (short)f2bf(f1.w);
        B[kc] = b;
    }

    const unsigned short* wt = wtb + r * HID * HID;
    float4v acc[8];
#pragma unroll
    for (int cb = 0; cb < 8; ++cb) acc[cb] = (float4v){0.f, 0.f, 0.f, 0.f};
#pragma unroll
    for (int cb = 0; cb < 8; ++cb) {
        const unsigned short* wrow = wt + (cb * 16 + m) * HID + quad * 8;
#pragma unroll
        for (int kc = 0; kc < 4; ++kc) {
            short8 A = *(const short8*)(wrow + kc * 32);
            acc[cb] = __builtin_amdgcn_mfma_f32_16x16x32_bf16(A, B[kc], acc[cb], 0, 0, 0);
        }
    }
    int node = strip * 16 + m;
    // packed bf16 store: 8 x uint2 per lane, channels cb*16+quad*4+{0..3} of this lane's node
    unsigned short* hrow = hb + ((long)r * N_NODES + node) * HID;
#pragma unroll
    for (int cb = 0; cb < 8; ++cb) {
        uint2 o;
        o.x = f2bf(acc[cb][0]) | ((unsigned)f2bf(acc[cb][1]) << 16);
        o.y = f2bf(acc[cb][2]) | ((unsigned)f2bf(acc[cb][3]) << 16);
        *(uint2*)(hrow + cb * 16 + quad * 4) = o;
    }
    // alpha epilogue: per-head dots with att vectors from fp32 acc, reduce across quads
    const float* ar = att_src + r * HID;
    const float* dr = att_dst + r * HID;
    float sa[4] = {0.f, 0.f, 0.f, 0.f}, sd[4] = {0.f, 0.f, 0.f, 0.f};
#pragma unroll
    for (int cb = 0; cb < 8; ++cb) {
        int hd = cb >> 1;
#pragma unroll
        for (int i = 0; i < 4; ++i) {
            int c = cb * 16 + quad * 4 + i;
            sa[hd] += acc[cb][i] * ar[c];
            sd[hd] += acc[cb][i] * dr[c];
        }
    }
#pragma unroll
    for (int hd = 0; hd < 4; ++hd) {
        sa[hd] += __shfl_xor(sa[hd], 16, 64); sa[hd] += __shfl_xor(sa[hd], 32, 64);
        sd[hd] += __shfl_xor(sd[hd], 16, 64); sd[hd] += __shfl_xor(sd[hd], 32, 64);
    }
    // quad q writes head q: 64 lanes -> 64 consecutive dwords (coalesced)
    float wa = quad == 0 ? sa[0] : quad == 1 ? sa[1] : quad == 2 ? sa[2] : sa[3];
    float wd = quad == 0 ? sd[0] : quad == 1 ? sd[1] : quad == 2 ? sd[2] : sd[3];
    asrc[((long)r * N_NODES + node) * 4 + quad] = wa;
    adst[((long)r * N_NODES + node) * 4 + quad] = wd;
}

// ---------------- fused gather-aggregate + gated combine + residual + LayerNorm ----------------
// One wave per dst node; quarter-waves (16 lanes) process slot entries.
// Fully-predicated 4-deep loop: always 4 row loads in flight (clamped indices, ev masked to 0)
// -> no serial cleanup loop, no quarter divergence.
__global__ __launch_bounds__(256) void aggr_kernel(const unsigned short* __restrict__ hb,
                                                   const int* __restrict__ cnt,
                                                   const unsigned short* __restrict__ slots,
                                                   const float* __restrict__ asrc,
                                                   const float* __restrict__ adst,
                                                   const float* __restrict__ gate,
                                                   const float* __restrict__ x,
                                                   const float* __restrict__ bias,
                                                   const float* __restrict__ ln_g,
                                                   const float* __restrict__ ln_b,
                                                   float* __restrict__ out) {
    int node = blockIdx.x * 4 + (threadIdx.x >> 6);
    int lane = threadIdx.x & 63;
    int q = lane >> 4;                 // quarter 0..3 -> edge slot
    int l = lane & 15;                 // channel group: channels l*8 .. l*8+7
    int hd = l >> 2;                   // head of those channels
    // inline softmax(gate)
    float g0 = gate[0], g1 = gate[1], g2 = gate[2];
    float mg = fmaxf(g0, fmaxf(g1, g2));
    float e0 = __expf(g0 - mg), e1 = __expf(g1 - mg), e2 = __expf(g2 - mg);
    float ginv = 1.f / (e0 + e1 + e2);
    float gwv[R_REL] = {e0 * ginv, e1 * ginv, e2 * ginv};

    float run0 = 0.f, run1 = 0.f, run2 = 0.f, run3 = 0.f;
    float run4 = 0.f, run5 = 0.f, run6 = 0.f, run7 = 0.f;
#pragma unroll
    for (int r = 0; r < R_REL; ++r) {
        const unsigned short* hr = hb + (long)r * N_NODES * HID;
        const float* as = asrc + (long)r * N_NODES * 4;
        const float* ad = adst + (long)r * N_NODES * 4;
        int cb = r * N_NODES + node;
        int deg = cnt[cb]; deg = deg < CAP ? deg : CAP;
        const unsigned short* sl = slots + (long)cb * CAP;
        float adv = ad[node * 4 + hd];
        float a0 = 0.f, a1 = 0.f, a2 = 0.f, a3 = 0.f;
        float a4 = 0.f, a5 = 0.f, a6 = 0.f, a7 = 0.f, den = 0.f;
        for (int i = q; i < deg; i += 16) {
            int j1 = i + 4, j2 = i + 8, j3 = i + 12;
            bool v1 = j1 < deg, v2 = j2 < deg, v3 = j3 < deg;
            int s0i = sl[i];
            int s1i = sl[v1 ? j1 : i];
            int s2i = sl[v2 ? j2 : i];
            int s3i = sl[v3 ? j3 : i];
            uint4 u0 = ((const uint4*)(hr + (long)s0i * HID))[l];
            uint4 u1 = ((const uint4*)(hr + (long)s1i * HID))[l];
            uint4 u2 = ((const uint4*)(hr + (long)s2i * HID))[l];
            uint4 u3 = ((const uint4*)(hr + (long)s3i * HID))[l];
            float t0 = as[s0i * 4 + hd] + adv; t0 = t0 > 0.f ? t0 : 0.2f * t0;
            float t1 = as[s1i * 4 + hd] + adv; t1 = t1 > 0.f ? t1 : 0.2f * t1;
            float t2 = as[s2i * 4 + hd] + adv; t2 = t2 > 0.f ? t2 : 0.2f * t2;
            float t3 = as[s3i * 4 + hd] + adv; t3 = t3 > 0.f ? t3 : 0.2f * t3;
            float ev0 = __expf(t0);
            float ev1 = v1 ? __expf(t1) : 0.f;
            float ev2 = v2 ? __expf(t2) : 0.f;
            float ev3 = v3 ? __expf(t3) : 0.f;
            a0 += ev0 * bf_lo(u0.x); a1 += ev0 * bf_hi(u0.x);
            a2 += ev0 * bf_lo(u0.y); a3 += ev0 * bf_hi(u0.y);
            a4 += ev0 * bf_lo(u0.z); a5 += ev0 * bf_hi(u0.z);
            a6 += ev0 * bf_lo(u0.w); a7 += ev0 * bf_hi(u0.w);
            a0 += ev1 * bf_lo(u1.x); a1 += ev1 * bf_hi(u1.x);
            a2 += ev1 * bf_lo(u1.y); a3 += ev1 * bf_hi(u1.y);
            a4 += ev1 * bf_lo(u1.z); a5 += ev1 * bf_hi(u1.z);
            a6 += ev1 * bf_lo(u1.w); a7 += ev1 * bf_hi(u1.w);
            a0 += ev2 * bf_lo(u2.x); a1 += ev2 * bf_hi(u2.x);
            a2 += ev2 * bf_lo(u2.y); a3 += ev2 * bf_hi(u2.y);
            a4 += ev2 * bf_lo(u2.z); a5 += ev2 * bf_hi(u2.z);
            a6 += ev2 * bf_lo(u2.w); a7 += ev2 * bf_hi(u2.w);
            a0 += ev3 * bf_lo(u3.x); a1 += ev3 * bf_hi(u3.x);
            a2 += ev3 * bf_lo(u3.y); a3 += ev3 * bf_hi(u3.y);
            a4 += ev3 * bf_lo(u3.z); a5 += ev3 * bf_hi(u3.z);
            a6 += ev3 * bf_lo(u3.w); a7 += ev3 * bf_hi(u3.w);
            den += (ev0 + ev1) + (ev2 + ev3);
        }
        // merge the 4 quarters (channels identical across quarters)
        a0 += __shfl_xor(a0, 16, 64); a0 += __shfl_xor(a0, 32, 64);
        a1 += __shfl_xor(a1, 16, 64); a1 += __shfl_xor(a1, 32, 64);
        a2 += __shfl_xor(a2, 16, 64); a2 += __shfl_xor(a2, 32, 64);
        a3 += __shfl_xor(a3, 16, 64); a3 += __shfl_xor(a3, 32, 64);
        a4 += __shfl_xor(a4, 16, 64); a4 += __shfl_xor(a4, 32, 64);
        a5 += __shfl_xor(a5, 16, 64); a5 += __shfl_xor(a5, 32, 64);
        a6 += __shfl_xor(a6, 16, 64); a6 += __shfl_xor(a6, 32, 64);
        a7 += __shfl_xor(a7, 16, 64); a7 += __shfl_xor(a7, 32, 64);
        den += __shfl_xor(den, 16, 64); den += __shfl_xor(den, 32, 64);
        float inv = gwv[r] / (den + 1e-16f);
        run0 += a0 * inv; run1 += a1 * inv; run2 += a2 * inv; run3 += a3 * inv;
        run4 += a4 * inv; run5 += a5 * inv; run6 += a6 * inv; run7 += a7 * inv;
    }
    // bias mix + residual (channels l*8 .. l*8+7)
    const float4* b4 = (const float4*)bias;
    float4 b00 = b4[2 * l], b01 = b4[2 * l + 1];
    float4 b10 = b4[32 + 2 * l], b11 = b4[32 + 2 * l + 1];
    float4 b20 = b4[64 + 2 * l], b21 = b4[64 + 2 * l + 1];
    float4 xv0 = ((const float4*)x)[(long)node * 32 + 2 * l];
    float4 xv1 = ((const float4*)x)[(long)node * 32 + 2 * l + 1];
    float v0 = run0 + xv0.x + gwv[0] * b00.x + gwv[1] * b10.x + gwv[2] * b20.x;
    float v1 = run1 + xv0.y + gwv[0] * b00.y + gwv[1] * b10.y + gwv[2] * b20.y;
    float v2 = run2 + xv0.z + gwv[0] * b00.z + gwv[1] * b10.z + gwv[2] * b20.z;
    float v3 = run3 + xv0.w + gwv[0] * b00.w + gwv[1] * b10.w + gwv[2] * b20.w;
    float v4 = run4 + xv1.x + gwv[0] * b01.x + gwv[1] * b11.x + gwv[2] * b21.x;
    float v5 = run5 + xv1.y + gwv[0] * b01.y + gwv[1] * b11.y + gwv[2] * b21.y;
    float v6 = run6 + xv1.z + gwv[0] * b01.z + gwv[1] * b11.z + gwv[2] * b21.z;
    float v7 = run7 + xv1.w + gwv[0] * b01.w + gwv[1] * b11.w + gwv[2] * b21.w;
    // LayerNorm: channels duplicated 4x across quarters -> divide by 4*HID
    float sum = v0 + v1 + v2 + v3 + v4 + v5 + v6 + v7;
    float sq = v0 * v0 + v1 * v1 + v2 * v2 + v3 * v3 + v4 * v4 + v5 * v5 + v6 * v6 + v7 * v7;
#pragma unroll
    for (int off = 32; off > 0; off >>= 1) {
        sum += __shfl_xor(sum, off, 64);
        sq  += __shfl_xor(sq, off, 64);
    }
    float mean = sum * (1.f / (4 * HID));
    float var = sq * (1.f / (4 * HID)) - mean * mean;
    float rstd = rsqrtf(var + 1e-5f);
    if (q == 0) {
        float4 gv0 = ((const float4*)ln_g)[2 * l], gv1 = ((const float4*)ln_g)[2 * l + 1];
        float4 bv0 = ((const float4*)ln_b)[2 * l], bv1 = ((const float4*)ln_b)[2 * l + 1];
        float4 o0, o1;
        o0.x = (v0 - mean) * rstd * gv0.x + bv0.x;
        o0.y = (v1 - mean) * rstd * gv0.y + bv0.y;
        o0.z = (v2 - mean) * rstd * gv0.z + bv0.z;
        o0.w = (v3 - mean) * rstd * gv0.w + bv0.w;
        o1.x = (v4 - mean) * rstd * gv1.x + bv1.x;
        o1.y = (v5 - mean) * rstd * gv1.y + bv1.y;
        o1.z = (v6 - mean) * rstd * gv1.z + bv1.z;
        o1.w = (v7 - mean) * rstd * gv1.w + bv1.w;
        ((float4*)out)[(long)node * 32 + 2 * l] = o0;
        ((float4*)out)[(long)node * 32 + 2 * l + 1] = o1;
    }
}

extern "C" void kernel_launch(void* const* d_in, const int* in_sizes, int n_in,
                              void* d_out, int out_size, void* d_ws, size_t ws_size,
                              hipStream_t stream) {
    const float* x        = (const float*)d_in[0];
    const int*   edge_idx = (const int*)d_in[1];
    // d_in[2] = edge_attr, unused (GATConv built without edge_dim)
    const float* W        = (const float*)d_in[3];
    const float* att_src  = (const float*)d_in[4];
    const float* att_dst  = (const float*)d_in[5];
    const float* bias     = (const float*)d_in[6];
    const float* gate     = (const float*)d_in[7];
    const float* ln_g     = (const float*)d_in[8];
    const float* ln_b     = (const float*)d_in[9];
    float* out = (float*)d_out;

    // workspace layout:
    // hb[3*N*128 bf16] | asrc[3*N*4 f] | adst[3*N*4 f] | cnt[3*N int]
    // | wtb[3*128*128 bf16] | slots[3*N*64 ushort]
    unsigned short* hb  = (unsigned short*)d_ws;
    float* asrc = (float*)(hb + (long)R_REL * N_NODES * HID);
    float* adst = asrc + R_REL * N_NODES * HEADS;
    int*   cnt  = (int*)(adst + R_REL * N_NODES * HEADS);
    unsigned short* wtb = (unsigned short*)(cnt + R_REL * N_NODES);
    unsigned short* slots = wtb + R_REL * HID * HID;

    hipMemsetAsync(cnt, 0, (size_t)R_REL * N_NODES * sizeof(int), stream);
    setup_scatter_kernel<<<SETUP_BLKS + SCAT_BLKS, 256, 0, stream>>>(
        W, gate, edge_idx, wtb, out + (long)N_NODES * HID, cnt, slots);
    gemm_kernel<<<GEMM_BLKS, 256, 0, stream>>>(x, wtb, hb, att_src, att_dst, asrc, adst);
    aggr_kernel<<<N_NODES / 4, 256, 0, stream>>>(hb, cnt, slots, asrc, adst, gate,
                                                 x, bias, ln_g, ln_b, out);
}

// Round 3
// 304.889 us; speedup vs baseline: 1.5346x; 1.5346x over previous
//
#include <hip/hip_runtime.h>

#define N_NODES 50000
#define E_EDGES 800000
#define R_REL 3
#define HID 128
#define HEADS 4
#define CAP 64               // per-(relation,node) slot capacity; P(indeg>63) ~ 1e-19
#define NPART 64             // dst partitions per relation
#define PSIZE 782            // ceil(50000/64)
#define CHUNKS_A 98          // phase-A chunks per relation (98*8192 >= 800000)
#define CAP_A 224            // bucket capacity per (chunk,partition); mean 128, ~8.5-sigma margin

typedef __attribute__((ext_vector_type(8))) short short8;   // 8 bf16 in 4 VGPRs
typedef __attribute__((ext_vector_type(4))) float float4v;  // MFMA C/D frag

__device__ __forceinline__ unsigned short f2bf(float f) {
    unsigned int u = __float_as_uint(f);
    u += 0x7fffu + ((u >> 16) & 1u);     // round-to-nearest-even
    return (unsigned short)(u >> 16);
}
__device__ __forceinline__ float bf_lo(unsigned int u) { return __uint_as_float(u << 16); }
__device__ __forceinline__ float bf_hi(unsigned int u) { return __uint_as_float(u & 0xffff0000u); }

// ---------------- dispatch 1: setup (W^T, gw) + phase-A edge bucketing ----------------
#define WCONV_T (R_REL * HID * HID)          // 49152
#define SETUP_BLKS 193                        // 192 for W^T + 1 spare thread block for gw
#define FILLA_BLKS (R_REL * CHUNKS_A)         // 294
__global__ __launch_bounds__(256) void setup_fillA_kernel(const float* __restrict__ W,
                                                          const float* __restrict__ gate,
                                                          const int* __restrict__ edge_idx,
                                                          unsigned short* __restrict__ wtb,
                                                          float* __restrict__ gw_out,
                                                          unsigned* __restrict__ regions,
                                                          int* __restrict__ bc) {
    __shared__ unsigned buf[NPART * CAP_A];   // 56 KB — only this dispatch pays it
    __shared__ int lcnt[NPART];
    int bid = blockIdx.x;
    if (bid < SETUP_BLKS) {
        int tid = bid * 256 + threadIdx.x;
        if (tid < WCONV_T) {
            int r = tid >> 14, rem = tid & 16383, n = rem >> 7, k = rem & 127;
            wtb[tid] = f2bf(W[r * 16384 + k * 128 + n]);   // wtb[r][n][k] = W[r][k][n]
        } else if (tid == WCONV_T) {
            float g0 = gate[0], g1 = gate[1], g2 = gate[2];
            float mg = fmaxf(g0, fmaxf(g1, g2));
            float e0 = __expf(g0 - mg), e1 = __expf(g1 - mg), e2 = __expf(g2 - mg);
            float inv = 1.f / (e0 + e1 + e2);
            gw_out[0] = e0 * inv; gw_out[1] = e1 * inv; gw_out[2] = e2 * inv;
        }
        return;
    }
    int fb = bid - SETUP_BLKS;
    int r = fb / CHUNKS_A, c = fb % CHUNKS_A;
    if (threadIdx.x < NPART) lcnt[threadIdx.x] = 0;
    __syncthreads();
    const int4* s4 = (const int4*)(edge_idx + (long)r * 2 * E_EDGES);
    const int4* d4 = (const int4*)(edge_idx + (long)r * 2 * E_EDGES + E_EDGES);
    int i0 = c * 2048;
    int i1 = i0 + 2048; if (i1 > E_EDGES / 4) i1 = E_EDGES / 4;
    for (int i = i0 + threadIdx.x; i < i1; i += 256) {
        int4 sv = s4[i];
        int4 dv = d4[i];
#pragma unroll
        for (int j = 0; j < 4; ++j) {
            int dst = (j == 0) ? dv.x : (j == 1) ? dv.y : (j == 2) ? dv.z : dv.w;
            int src = (j == 0) ? sv.x : (j == 1) ? sv.y : (j == 2) ? sv.z : sv.w;
            int p = dst / PSIZE;
            int reldst = dst - p * PSIZE;
            int pos = atomicAdd(&lcnt[p], 1);
            if (pos < CAP_A) buf[p * CAP_A + pos] = ((unsigned)reldst << 16) | (unsigned)src;
        }
    }
    __syncthreads();
    long rbase = (long)(r * CHUNKS_A + c) * NPART;
    int wv = threadIdx.x >> 6, ln = threadIdx.x & 63;
    for (int p = wv; p < NPART; p += 4) {      // wave-parallel drain
        int n = lcnt[p]; if (n > CAP_A) n = CAP_A;
        unsigned* dp = regions + (rbase + p) * CAP_A;
        for (int i = ln; i < n; i += 64) dp[i] = buf[p * CAP_A + i];
    }
    if (threadIdx.x < NPART) {
        int n = lcnt[threadIdx.x]; if (n > CAP_A) n = CAP_A;
        bc[rbase + threadIdx.x] = n;
    }
}

// ---------------- dispatch 2: phase-B slot build (blocks 0..191) + MFMA GEMM/alpha (rest) ----------------
// FillB: block (r,p) exclusively owns dst range [p*PSIZE, ...); 4 waves drain 4 chunk-lists
//        concurrently via LDS atomics; slot slice (~100 KB) stays L2-dense.
// GEMM:  A = W^T (rows=channels), B = x^T in-register bf16 -> D[channel reg][node lane].
#define FILLB_BLKS (R_REL * NPART)            // 192
#define STRIPS 3125
#define BLK_PER_REL 782                       // ceil(3125/4)
#define GEMM_BLKS (R_REL * BLK_PER_REL)       // 2346
__global__ __launch_bounds__(256) void gemm_fillB_kernel(const float* __restrict__ x,
                                                         const unsigned short* __restrict__ wtb,
                                                         unsigned short* __restrict__ hb,
                                                         const float* __restrict__ att_src,
                                                         const float* __restrict__ att_dst,
                                                         float* __restrict__ asrc,
                                                         float* __restrict__ adst,
                                                         const unsigned* __restrict__ regions,
                                                         const int* __restrict__ bc,
                                                         int* __restrict__ cnt,
                                                         unsigned short* __restrict__ slots) {
    __shared__ int lc[PSIZE];                 // 3.1 KB — does not bind gemm occupancy
    int bid = blockIdx.x;
    if (bid < FILLB_BLKS) {
        int r = bid / NPART, p = bid % NPART;
        int base = p * PSIZE;
        int psz = N_NODES - base; if (psz > PSIZE) psz = PSIZE;
        if (psz < 0) psz = 0;
        for (int i = threadIdx.x; i < PSIZE; i += 256) lc[i] = 0;
        __syncthreads();
        int wv = threadIdx.x >> 6, ln = threadIdx.x & 63;
        for (int c = wv; c < CHUNKS_A; c += 4) {   // wave-per-chunk: 4 lists in flight
            long rb = (long)(r * CHUNKS_A + c) * NPART + p;
            int n = bc[rb];
            const unsigned* sp = regions + rb * CAP_A;
            for (int i = ln; i < n; i += 64) {
                unsigned e = sp[i];
                int reldst = e >> 16;
                int src = e & 0xffff;
                int pos = atomicAdd(&lc[reldst], 1);   // LDS atomic — workgroup scope
                if (pos < CAP)
                    slots[((long)(r * N_NODES + base + reldst)) * CAP + pos] = (unsigned short)src;
            }
        }
        __syncthreads();
        for (int i = threadIdx.x; i < psz; i += 256)
            cnt[r * N_NODES + base + i] = lc[i];
        return;
    }
    int gb = bid - FILLB_BLKS;
    int r = gb / BLK_PER_REL;
    int sb = gb % BLK_PER_REL;
    int strip = sb * 4 + (threadIdx.x >> 6);
    if (strip >= STRIPS) return;
    int lane = threadIdx.x & 63;
    int m = lane & 15, quad = lane >> 4;

    // B-operand: lane m reads fp32 row strip*16+m, k-chunk quad*8, converts to bf16 in-register
    const float* xrow = x + (long)(strip * 16 + m) * HID + quad * 8;
    short8 B[4];
#pragma unroll
    for (int kc = 0; kc < 4; ++kc) {
        float4 f0 = *(const float4*)(xrow + kc * 32);
        float4 f1 = *(const float4*)(xrow + kc * 32 + 4);
        short8 b;
        b[0] = (short)f2bf(f0.x); b[1] = (short)f2bf(f0.y);
        b[2] = (short)f2bf(f0.z); b[3] = (short)f2bf(f0.w);
        b[4] = (short)f2bf(f1.x); b[5] = (short)f2bf(f1.y);
        b[6] = (short)f2bf(f1.z); b[7] = (short)f2bf(f1.w);
        B[kc] = b;
    }

    const unsigned short* wt = wtb + r * HID * HID;
    float4v acc[8];
#pragma unroll
    for (int cb = 0; cb < 8; ++cb) acc[cb] = (float4v){0.f, 0.f, 0.f, 0.f};
#pragma unroll
    for (int cb = 0; cb < 8; ++cb) {
        const unsigned short* wrow = wt + (cb * 16 + m) * HID + quad * 8;
#pragma unroll
        for (int kc = 0; kc < 4; ++kc) {
            short8 A = *(const short8*)(wrow + kc * 32);
            acc[cb] = __builtin_amdgcn_mfma_f32_16x16x32_bf16(A, B[kc], acc[cb], 0, 0, 0);
        }
    }
    int node = strip * 16 + m;
    // packed bf16 store: 8 x uint2 per lane, channels cb*16+quad*4+{0..3} of this lane's node
    unsigned short* hrow = hb + ((long)r * N_NODES + node) * HID;
#pragma unroll
    for (int cb = 0; cb < 8; ++cb) {
        uint2 o;
        o.x = f2bf(acc[cb][0]) | ((unsigned)f2bf(acc[cb][1]) << 16);
        o.y = f2bf(acc[cb][2]) | ((unsigned)f2bf(acc[cb][3]) << 16);
        *(uint2*)(hrow + cb * 16 + quad * 4) = o;
    }
    // alpha epilogue: per-head dots with att vectors from fp32 acc, reduce across quads
    const float* ar = att_src + r * HID;
    const float* dr = att_dst + r * HID;
    float sa[4] = {0.f, 0.f, 0.f, 0.f}, sd[4] = {0.f, 0.f, 0.f, 0.f};
#pragma unroll
    for (int cb = 0; cb < 8; ++cb) {
        int hd = cb >> 1;
#pragma unroll
        for (int i = 0; i < 4; ++i) {
            int c = cb * 16 + quad * 4 + i;
            sa[hd] += acc[cb][i] * ar[c];
            sd[hd] += acc[cb][i] * dr[c];
        }
    }
#pragma unroll
    for (int hd = 0; hd < 4; ++hd) {
        sa[hd] += __shfl_xor(sa[hd], 16, 64); sa[hd] += __shfl_xor(sa[hd], 32, 64);
        sd[hd] += __shfl_xor(sd[hd], 16, 64); sd[hd] += __shfl_xor(sd[hd], 32, 64);
    }
    // quad q writes head q: 64 lanes -> 64 consecutive dwords (coalesced)
    float wa = quad == 0 ? sa[0] : quad == 1 ? sa[1] : quad == 2 ? sa[2] : sa[3];
    float wd = quad == 0 ? sd[0] : quad == 1 ? sd[1] : quad == 2 ? sd[2] : sd[3];
    asrc[((long)r * N_NODES + node) * 4 + quad] = wa;
    adst[((long)r * N_NODES + node) * 4 + quad] = wd;
}

// ---------------- fused gather-aggregate + gated combine + residual + LayerNorm ----------------
// One wave per dst node; quarter-waves (16 lanes) process slot entries.
// Slot row pre-loaded as uint2 packs (pack p = slots 4p..4p+3; quarter q owns packs q,q+4,q+8,q+12);
// <=4 fully-unrolled rounds gated by wave-uniform deg tests; per-slot predication with
// clamped-to-valid fallback index (ev masked to 0; no 0*Inf).
__global__ __launch_bounds__(256) void aggr_kernel(const unsigned short* __restrict__ hb,
                                                   const int* __restrict__ cnt,
                                                   const unsigned short* __restrict__ slots,
                                                   const float* __restrict__ asrc,
                                                   const float* __restrict__ adst,
                                                   const float* __restrict__ gate,
                                                   const float* __restrict__ x,
                                                   const float* __restrict__ bias,
                                                   const float* __restrict__ ln_g,
                                                   const float* __restrict__ ln_b,
                                                   float* __restrict__ out) {
    int node = blockIdx.x * 4 + (threadIdx.x >> 6);
    int lane = threadIdx.x & 63;
    int q = lane >> 4;                 // quarter 0..3
    int l = lane & 15;                 // channel group: channels l*8 .. l*8+7
    int hd = l >> 2;                   // head of those channels
    // inline softmax(gate)
    float g0 = gate[0], g1 = gate[1], g2 = gate[2];
    float mg = fmaxf(g0, fmaxf(g1, g2));
    float e0 = __expf(g0 - mg), e1 = __expf(g1 - mg), e2 = __expf(g2 - mg);
    float ginv = 1.f / (e0 + e1 + e2);
    float gwv[R_REL] = {e0 * ginv, e1 * ginv, e2 * ginv};

    float run0 = 0.f, run1 = 0.f, run2 = 0.f, run3 = 0.f;
    float run4 = 0.f, run5 = 0.f, run6 = 0.f, run7 = 0.f;
#pragma unroll
    for (int r = 0; r < R_REL; ++r) {
        const unsigned short* hr = hb + (long)r * N_NODES * HID;
        const float* as = asrc + (long)r * N_NODES * 4;
        const float* ad = adst + (long)r * N_NODES * 4;
        int cb = r * N_NODES + node;
        int deg = cnt[cb]; deg = deg < CAP ? deg : CAP;
        const unsigned short* sl = slots + (long)cb * CAP;
        const uint2* sl2 = (const uint2*)sl;   // pack p = slots 4p..4p+3 (8B aligned)
        float adv = ad[node * 4 + hd];
        float a0 = 0.f, a1 = 0.f, a2 = 0.f, a3 = 0.f;
        float a4 = 0.f, a5 = 0.f, a6 = 0.f, a7 = 0.f, den = 0.f;
        if (deg > 0) {
            int sfb = sl[0];                   // guaranteed-valid fallback slot
            uint2 P0 = sl2[q];
            uint2 P1 = sl2[q + 4];
            uint2 P2 = sl2[q + 8];
            uint2 P3 = sl2[q + 12];
#define AGGR_ROUND(P, BASE)                                                          \
            {                                                                        \
                int b = (BASE) + 4 * q;                                              \
                int s0 = (int)((P).x & 0xffffu), s1 = (int)((P).x >> 16);            \
                int s2 = (int)((P).y & 0xffffu), s3 = (int)((P).y >> 16);            \
                bool v0 = b < deg, v1 = b + 1 < deg, v2 = b + 2 < deg, v3 = b + 3 < deg; \
                s0 = v0 ? s0 : sfb; s1 = v1 ? s1 : sfb;                              \
                s2 = v2 ? s2 : sfb; s3 = v3 ? s3 : sfb;                              \
                uint4 u0 = ((const uint4*)(hr + (long)s0 * HID))[l];                 \
                uint4 u1 = ((const uint4*)(hr + (long)s1 * HID))[l];                 \
                uint4 u2 = ((const uint4*)(hr + (long)s2 * HID))[l];                 \
                uint4 u3 = ((const uint4*)(hr + (long)s3 * HID))[l];                 \
                float t0 = as[s0 * 4 + hd] + adv; t0 = t0 > 0.f ? t0 : 0.2f * t0;    \
                float t1 = as[s1 * 4 + hd] + adv; t1 = t1 > 0.f ? t1 : 0.2f * t1;    \
                float t2 = as[s2 * 4 + hd] + adv; t2 = t2 > 0.f ? t2 : 0.2f * t2;    \
                float t3 = as[s3 * 4 + hd] + adv; t3 = t3 > 0.f ? t3 : 0.2f * t3;    \
                float ev0 = v0 ? __expf(t0) : 0.f;                                   \
                float ev1 = v1 ? __expf(t1) : 0.f;                                   \
                float ev2 = v2 ? __expf(t2) : 0.f;                                   \
                float ev3 = v3 ? __expf(t3) : 0.f;                                   \
                a0 += ev0 * bf_lo(u0.x); a1 += ev0 * bf_hi(u0.x);                    \
                a2 += ev0 * bf_lo(u0.y); a3 += ev0 * bf_hi(u0.y);                    \
                a4 += ev0 * bf_lo(u0.z); a5 += ev0 * bf_hi(u0.z);                    \
                a6 += ev0 * bf_lo(u0.w); a7 += ev0 * bf_hi(u0.w);                    \
                a0 += ev1 * bf_lo(u1.x); a1 += ev1 * bf_hi(u1.x);                    \
                a2 += ev1 * bf_lo(u1.y); a3 += ev1 * bf_hi(u1.y);                    \
                a4 += ev1 * bf_lo(u1.z); a5 += ev1 * bf_hi(u1.z);                    \
                a6 += ev1 * bf_lo(u1.w); a7 += ev1 * bf_hi(u1.w);                    \
                a0 += ev2 * bf_lo(u2.x); a1 += ev2 * bf_hi(u2.x);                    \
                a2 += ev2 * bf_lo(u2.y); a3 += ev2 * bf_hi(u2.y);                    \
                a4 += ev2 * bf_lo(u2.z); a5 += ev2 * bf_hi(u2.z);                    \
                a6 += ev2 * bf_lo(u2.w); a7 += ev2 * bf_hi(u2.w);                    \
                a0 += ev3 * bf_lo(u3.x); a1 += ev3 * bf_hi(u3.x);                    \
                a2 += ev3 * bf_lo(u3.y); a3 += ev3 * bf_hi(u3.y);                    \
                a4 += ev3 * bf_lo(u3.z); a5 += ev3 * bf_hi(u3.z);                    \
                a6 += ev3 * bf_lo(u3.w); a7 += ev3 * bf_hi(u3.w);                    \
                den += (ev0 + ev1) + (ev2 + ev3);                                    \
            }
            AGGR_ROUND(P0, 0)
            if (deg > 16) { AGGR_ROUND(P1, 16) }
            if (deg > 32) { AGGR_ROUND(P2, 32) }
            if (deg > 48) { AGGR_ROUND(P3, 48) }
#undef AGGR_ROUND
        }
        // merge the 4 quarters (channels identical across quarters)
        a0 += __shfl_xor(a0, 16, 64); a0 += __shfl_xor(a0, 32, 64);
        a1 += __shfl_xor(a1, 16, 64); a1 += __shfl_xor(a1, 32, 64);
        a2 += __shfl_xor(a2, 16, 64); a2 += __shfl_xor(a2, 32, 64);
        a3 += __shfl_xor(a3, 16, 64); a3 += __shfl_xor(a3, 32, 64);
        a4 += __shfl_xor(a4, 16, 64); a4 += __shfl_xor(a4, 32, 64);
        a5 += __shfl_xor(a5, 16, 64); a5 += __shfl_xor(a5, 32, 64);
        a6 += __shfl_xor(a6, 16, 64); a6 += __shfl_xor(a6, 32, 64);
        a7 += __shfl_xor(a7, 16, 64); a7 += __shfl_xor(a7, 32, 64);
        den += __shfl_xor(den, 16, 64); den += __shfl_xor(den, 32, 64);
        float inv = gwv[r] / (den + 1e-16f);
        run0 += a0 * inv; run1 += a1 * inv; run2 += a2 * inv; run3 += a3 * inv;
        run4 += a4 * inv; run5 += a5 * inv; run6 += a6 * inv; run7 += a7 * inv;
    }
    // bias mix + residual (channels l*8 .. l*8+7)
    const float4* b4 = (const float4*)bias;
    float4 b00 = b4[2 * l], b01 = b4[2 * l + 1];
    float4 b10 = b4[32 + 2 * l], b11 = b4[32 + 2 * l + 1];
    float4 b20 = b4[64 + 2 * l], b21 = b4[64 + 2 * l + 1];
    float4 xv0 = ((const float4*)x)[(long)node * 32 + 2 * l];
    float4 xv1 = ((const float4*)x)[(long)node * 32 + 2 * l + 1];
    float v0 = run0 + xv0.x + gwv[0] * b00.x + gwv[1] * b10.x + gwv[2] * b20.x;
    float v1 = run1 + xv0.y + gwv[0] * b00.y + gwv[1] * b10.y + gwv[2] * b20.y;
    float v2 = run2 + xv0.z + gwv[0] * b00.z + gwv[1] * b10.z + gwv[2] * b20.z;
    float v3 = run3 + xv0.w + gwv[0] * b00.w + gwv[1] * b10.w + gwv[2] * b20.w;
    float v4 = run4 + xv1.x + gwv[0] * b01.x + gwv[1] * b11.x + gwv[2] * b21.x;
    float v5 = run5 + xv1.y + gwv[0] * b01.y + gwv[1] * b11.y + gwv[2] * b21.y;
    float v6 = run6 + xv1.z + gwv[0] * b01.z + gwv[1] * b11.z + gwv[2] * b21.z;
    float v7 = run7 + xv1.w + gwv[0] * b01.w + gwv[1] * b11.w + gwv[2] * b21.w;
    // LayerNorm: channels duplicated 4x across quarters -> divide by 4*HID
    float sum = v0 + v1 + v2 + v3 + v4 + v5 + v6 + v7;
    float sq = v0 * v0 + v1 * v1 + v2 * v2 + v3 * v3 + v4 * v4 + v5 * v5 + v6 * v6 + v7 * v7;
#pragma unroll
    for (int off = 32; off > 0; off >>= 1) {
        sum += __shfl_xor(sum, off, 64);
        sq  += __shfl_xor(sq, off, 64);
    }
    float mean = sum * (1.f / (4 * HID));
    float var = sq * (1.f / (4 * HID)) - mean * mean;
    float rstd = rsqrtf(var + 1e-5f);
    if (q == 0) {
        float4 gv0 = ((const float4*)ln_g)[2 * l], gv1 = ((const float4*)ln_g)[2 * l + 1];
        float4 bv0 = ((const float4*)ln_b)[2 * l], bv1 = ((const float4*)ln_b)[2 * l + 1];
        float4 o0, o1;
        o0.x = (v0 - mean) * rstd * gv0.x + bv0.x;
        o0.y = (v1 - mean) * rstd * gv0.y + bv0.y;
        o0.z = (v2 - mean) * rstd * gv0.z + bv0.z;
        o0.w = (v3 - mean) * rstd * gv0.w + bv0.w;
        o1.x = (v4 - mean) * rstd * gv1.x + bv1.x;
        o1.y = (v5 - mean) * rstd * gv1.y + bv1.y;
        o1.z = (v6 - mean) * rstd * gv1.z + bv1.z;
        o1.w = (v7 - mean) * rstd * gv1.w + bv1.w;
        ((float4*)out)[(long)node * 32 + 2 * l] = o0;
        ((float4*)out)[(long)node * 32 + 2 * l + 1] = o1;
    }
}

extern "C" void kernel_launch(void* const* d_in, const int* in_sizes, int n_in,
                              void* d_out, int out_size, void* d_ws, size_t ws_size,
                              hipStream_t stream) {
    const float* x        = (const float*)d_in[0];
    const int*   edge_idx = (const int*)d_in[1];
    // d_in[2] = edge_attr, unused (GATConv built without edge_dim)
    const float* W        = (const float*)d_in[3];
    const float* att_src  = (const float*)d_in[4];
    const float* att_dst  = (const float*)d_in[5];
    const float* bias     = (const float*)d_in[6];
    const float* gate     = (const float*)d_in[7];
    const float* ln_g     = (const float*)d_in[8];
    const float* ln_b     = (const float*)d_in[9];
    float* out = (float*)d_out;

    // workspace layout (~80 MB):
    // hb[3*N*128 bf16] | asrc[3*N*4 f] | adst[3*N*4 f] | cnt[3*N int]
    // | wtb[3*128*128 bf16] | slots[3*N*64 ushort] | regions[3*98*64*224 uint] | bc[18816 int]
    unsigned short* hb  = (unsigned short*)d_ws;
    float* asrc = (float*)(hb + (long)R_REL * N_NODES * HID);
    float* adst = asrc + R_REL * N_NODES * HEADS;
    int*   cnt  = (int*)(adst + R_REL * N_NODES * HEADS);
    unsigned short* wtb = (unsigned short*)(cnt + R_REL * N_NODES);
    unsigned short* slots = wtb + R_REL * HID * HID;
    unsigned* regions = (unsigned*)(slots + (long)R_REL * N_NODES * CAP);
    int* bc = (int*)(regions + (long)R_REL * CHUNKS_A * NPART * CAP_A);

    setup_fillA_kernel<<<SETUP_BLKS + FILLA_BLKS, 256, 0, stream>>>(
        W, gate, edge_idx, wtb, out + (long)N_NODES * HID, regions, bc);
    gemm_fillB_kernel<<<FILLB_BLKS + GEMM_BLKS, 256, 0, stream>>>(
        x, wtb, hb, att_src, att_dst, asrc, adst, regions, bc, cnt, slots);
    aggr_kernel<<<N_NODES / 4, 256, 0, stream>>>(hb, cnt, slots, asrc, adst, gate,
                                                 x, bias, ln_g, ln_b, out);
}